// Round 4
// baseline (179.640 us; speedup 1.0000x reference)
//
#include <hip/hip_runtime.h>
#include <hip/hip_bf16.h>
#include <cstdint>
#include <cstddef>

// ---------------- wave helpers (wave64) ----------------
__device__ __forceinline__ float wave_max_f(float v){
  #pragma unroll
  for (int m = 32; m; m >>= 1) v = fmaxf(v, __shfl_xor(v, m));
  return v;
}
__device__ __forceinline__ float wave_sum_f(float v){
  #pragma unroll
  for (int m = 32; m; m >>= 1) v += __shfl_xor(v, m);
  return v;
}
__device__ __forceinline__ int wave_sum_i(int v){
  #pragma unroll
  for (int m = 32; m; m >>= 1) v += __shfl_xor(v, m);
  return v;
}

// ---------------- _sample_early: gather + normalize ----------------
template<int C, int LOGHW>
__global__ __launch_bounds__(64)
void sample_kernel(const float* __restrict__ feat, const int* __restrict__ pid,
                   float* __restrict__ out){
  const int r = blockIdx.x;          // 0..127
  const int b = r >> 6, p = r & 63;
  const int lane = threadIdx.x;      // 0..63
  const int l = pid[p];
  const float* fb = feat + (((size_t)b * C) << LOGHW);
  constexpr int V = C / 64;
  float v[V];
  float sq = 0.f;
  #pragma unroll
  for (int i = 0; i < V; ++i){
    const int c = lane + 64 * i;
    v[i] = fb[(((size_t)c) << LOGHW) + l];
    sq += v[i] * v[i];
  }
  sq = wave_sum_f(sq);
  const float nrm = fmaxf(sqrtf(sq), 1e-7f);
  #pragma unroll
  for (int i = 0; i < V; ++i)
    out[(size_t)r * C + lane + 64 * i] = v[i] / nrm;
}

// ---------------- qs_attn constants ----------------
#define C3   256
#define HW3  4096
#define NP   64

// ---------------- local dots (scrambled faithful mapping) ----------------
// wave per (b,h,k2); lanes = w. f = k2*256 + c2, c2 runs 0..255 exactly;
// (c,k) = (f/49, f%49) spans <=7 channels with k cycling. Fully unroll
// 7 channels x 49 compile-time k-steps with wave-uniform scalar guards.
// Window rows in registers (7 loads/channel), shifted values via __shfl.
// Accumulation order = ascending f = identical to the simple c2 loop.
__global__ __launch_bounds__(256)
void ldots_kernel(const float* __restrict__ feat3, float* __restrict__ dotsl){
  const int blk = blockIdx.x;
  const int kg = blk % 13;
  const int bh = blk / 13;
  const int b = bh >> 6, h = bh & 63;
  const int tid = threadIdx.x, wid = tid >> 6, lane = tid & 63;
  const int k2 = kg * 4 + wid;
  if (k2 >= 49) return;
  const float* fb = feat3 + ((size_t)b << 20);
  const int w = lane;

  const int f0 = k2 << 8;
  const int c0 = __builtin_amdgcn_readfirstlane(f0 / 49);
  const int k0 = __builtin_amdgcn_readfirstlane(f0 - (f0 / 49) * 49);

  // per-kj clamped shuffle lane + validity (kj is compile-time at use sites)
  int  sidx[7];
  bool okj[7];
  #pragma unroll
  for (int kj = 0; kj < 7; ++kj){
    const int s = w + kj - 3;
    okj[kj]  = (unsigned)s < 64u;
    sidx[kj] = s < 0 ? 0 : (s > 63 ? 63 : s);
  }

  const float* frp = fb + (h << 6) + w;   // fr[l, c2] = frp[c2 << 12]
  float r0, r1, r2, r3, r4, r5, r6;
  float acc = 0.f;

#define LDROWS(CC) do{                                                   \
    if ((CC)*49 + 48 >= k0 && (CC)*49 < k0 + 256){                       \
      const float* chan = fb + ((size_t)(c0 + (CC)) << 12) + w;          \
      r0 = (h >= 3)  ? chan[(h-3)<<6] : 0.f;                             \
      r1 = (h >= 2)  ? chan[(h-2)<<6] : 0.f;                             \
      r2 = (h >= 1)  ? chan[(h-1)<<6] : 0.f;                             \
      r3 =             chan[(h  )<<6];                                   \
      r4 = (h <= 62) ? chan[(h+1)<<6] : 0.f;                             \
      r5 = (h <= 61) ? chan[(h+2)<<6] : 0.f;                             \
      r6 = (h <= 60) ? chan[(h+3)<<6] : 0.f;                             \
    }                                                                    \
  }while(0)

#define KSTEP(CC,K,RI,KJ) do{                                            \
    if ((CC)*49 + (K) >= k0 && (CC)*49 + (K) < k0 + 256){                \
      float v = __shfl(RI, sidx[KJ]);                                    \
      v = okj[KJ] ? v : 0.f;                                             \
      acc = fmaf(v, frp[((CC)*49 + (K) - k0) << 12], acc);               \
    }                                                                    \
  }while(0)

#define CHAN(CC)                                                          \
  LDROWS(CC);                                                             \
  KSTEP(CC, 0,r0,0); KSTEP(CC, 1,r0,1); KSTEP(CC, 2,r0,2); KSTEP(CC, 3,r0,3); \
  KSTEP(CC, 4,r0,4); KSTEP(CC, 5,r0,5); KSTEP(CC, 6,r0,6);                \
  KSTEP(CC, 7,r1,0); KSTEP(CC, 8,r1,1); KSTEP(CC, 9,r1,2); KSTEP(CC,10,r1,3); \
  KSTEP(CC,11,r1,4); KSTEP(CC,12,r1,5); KSTEP(CC,13,r1,6);                \
  KSTEP(CC,14,r2,0); KSTEP(CC,15,r2,1); KSTEP(CC,16,r2,2); KSTEP(CC,17,r2,3); \
  KSTEP(CC,18,r2,4); KSTEP(CC,19,r2,5); KSTEP(CC,20,r2,6);                \
  KSTEP(CC,21,r3,0); KSTEP(CC,22,r3,1); KSTEP(CC,23,r3,2); KSTEP(CC,24,r3,3); \
  KSTEP(CC,25,r3,4); KSTEP(CC,26,r3,5); KSTEP(CC,27,r3,6);                \
  KSTEP(CC,28,r4,0); KSTEP(CC,29,r4,1); KSTEP(CC,30,r4,2); KSTEP(CC,31,r4,3); \
  KSTEP(CC,32,r4,4); KSTEP(CC,33,r4,5); KSTEP(CC,34,r4,6);                \
  KSTEP(CC,35,r5,0); KSTEP(CC,36,r5,1); KSTEP(CC,37,r5,2); KSTEP(CC,38,r5,3); \
  KSTEP(CC,39,r5,4); KSTEP(CC,40,r5,5); KSTEP(CC,41,r5,6);                \
  KSTEP(CC,42,r6,0); KSTEP(CC,43,r6,1); KSTEP(CC,44,r6,2); KSTEP(CC,45,r6,3); \
  KSTEP(CC,46,r6,4); KSTEP(CC,47,r6,5); KSTEP(CC,48,r6,6);

  CHAN(0) CHAN(1) CHAN(2) CHAN(3) CHAN(4) CHAN(5) CHAN(6)

#undef CHAN
#undef KSTEP
#undef LDROWS

  dotsl[(((size_t)(b * 49 + k2)) << 12) + (h << 6) + w] = acc;
}

// ---------------- local entropy (softmax over 49, k-major layout) ----------
__global__ __launch_bounds__(256)
void lent_kernel(const float* __restrict__ dotsl, float* __restrict__ ent){
  const int blk = blockIdx.x;       // 32
  const int b = blk >> 4;
  const int l = ((blk & 15) << 8) + threadIdx.x;
  const float* dl = dotsl + (((size_t)b * 49) << 12);
  float m = -INFINITY;
  #pragma unroll
  for (int k = 0; k < 49; ++k) m = fmaxf(m, dl[((size_t)k << 12) + l]);
  float s = 0.f, ts = 0.f;
  #pragma unroll
  for (int k = 0; k < 49; ++k){
    const float d = dl[((size_t)k << 12) + l] - m;
    const float e = expf(d);
    s += e; ts += e * d;
  }
  ent[b * HW3 + l] = logf(s) - ts / s;
}

// ---------------- rank-based top-64 selection (stable, exact) -------------
__global__ __launch_bounds__(256)
void rank_select_kernel(const float* __restrict__ ent, int* __restrict__ idx){
  __shared__ unsigned long long keys[HW3];   // 32 KB
  const int blk = blockIdx.x;
  const int b  = blk >> 6;
  const int cg = blk & 63;                   // 64 candidates per block
  const int t = threadIdx.x, wid = t >> 6, lane = t & 63;
  for (int i = t; i < HW3; i += 256){
    const float e = ent[b * HW3 + i];
    unsigned u = __float_as_uint(e);
    u = (u & 0x80000000u) ? ~u : (u | 0x80000000u);
    keys[i] = ((unsigned long long)u << 32) | (unsigned)i;
  }
  __syncthreads();
  #pragma unroll
  for (int j = 0; j < 16; ++j){
    const int cand = (cg << 6) + (wid << 4) + j;
    const unsigned long long kc = keys[cand];
    int cnt = 0;
    #pragma unroll 8
    for (int i = lane; i < HW3; i += 64)
      cnt += (keys[i] < kc) ? 1 : 0;
    cnt = wave_sum_i(cnt);
    if (lane == 0 && cnt < NP) idx[b * NP + cnt] = cand;
  }
}

// ---------------- global dots: grid (b,p) x 16 l-chunks -------------------
__global__ __launch_bounds__(256)
void gdots_kernel(const float* __restrict__ feat3, const int* __restrict__ idx,
                  float* __restrict__ dg, float* __restrict__ bmax){
  __shared__ float q_sh[C3];
  __shared__ float red[4];
  const int blk = blockIdx.x;       // 2048
  const int bp = blk >> 4, lc = blk & 15;
  const int b = bp >> 6;
  const int t = threadIdx.x, lane = t & 63, wid = t >> 6;
  const float* fb = feat3 + ((size_t)b << 20);
  const int pidx = idx[bp];
  q_sh[t] = fb[((size_t)t << 12) + pidx];
  __syncthreads();
  const int l = (lc << 8) + t;
  float acc = 0.f;
  #pragma unroll 8
  for (int c = 0; c < C3; ++c) acc += fb[((size_t)c << 12) + l] * q_sh[c];
  dg[((size_t)bp << 12) + l] = acc;
  const float m = wave_max_f(acc);
  if (lane == 0) red[wid] = m;
  __syncthreads();
  if (t == 0) bmax[bp * 16 + lc] = fmaxf(fmaxf(red[0], red[1]), fmaxf(red[2], red[3]));
}

// ---------------- global softmax stats ----------------
__global__ __launch_bounds__(256)
void gsm_kernel(const float* __restrict__ dg, const float* __restrict__ bmax,
                float* __restrict__ mrow, float* __restrict__ srow){
  __shared__ float red[4];
  const int bp = blockIdx.x, t = threadIdx.x, lane = t & 63, wid = t >> 6;
  float m = -INFINITY;
  #pragma unroll
  for (int i = 0; i < 16; ++i) m = fmaxf(m, bmax[bp * 16 + i]);
  float s = 0.f;
  #pragma unroll
  for (int i = 0; i < 16; ++i) s += expf(dg[((size_t)bp << 12) + (i << 8) + t] - m);
  s = wave_sum_f(s);
  if (lane == 0) red[wid] = s;
  __syncthreads();
  if (t == 0){
    mrow[bp] = m;
    srow[bp] = 1.f / (red[0] + red[1] + red[2] + red[3]);
  }
}

// ---------------- PV: grid (b,p) x 8 channel-groups -----------------------
__global__ __launch_bounds__(256)
void pv_kernel(const float* __restrict__ feat3, const float* __restrict__ dg,
               const float* __restrict__ mrow, const float* __restrict__ srow,
               float* __restrict__ outraw){
  __shared__ float p_sh[HW3];
  const int blk = blockIdx.x;       // 1024
  const int bp = blk >> 3, cg = blk & 7;
  const int b = bp >> 6;
  const int t = threadIdx.x, lane = t & 63, wid = t >> 6;
  const float* fb = feat3 + ((size_t)b << 20);
  const float m = mrow[bp], inv = srow[bp];
  #pragma unroll
  for (int i = 0; i < 16; ++i){
    const int l = (i << 8) + t;
    p_sh[l] = expf(dg[((size_t)bp << 12) + l] - m) * inv;
  }
  __syncthreads();
  const float4* pv4 = reinterpret_cast<const float4*>(p_sh);
  #pragma unroll
  for (int j = 0; j < 8; ++j){
    const int c = (cg << 5) + (wid << 3) + j;
    const float4* rv = reinterpret_cast<const float4*>(fb + ((size_t)c << 12));
    float s = 0.f;
    #pragma unroll
    for (int i = 0; i < 16; ++i){
      const float4 a = rv[(i << 6) + lane];
      const float4 pp = pv4[(i << 6) + lane];
      s += a.x * pp.x + a.y * pp.y + a.z * pp.z + a.w * pp.w;
    }
    s = wave_sum_f(s);
    if (lane == 0) outraw[bp * C3 + c] = s;
  }
}

// ---------------- normalize rows of 256 ----------------
__global__ __launch_bounds__(256)
void norm_kernel(const float* __restrict__ outraw, float* __restrict__ out3){
  __shared__ float red[4];
  const int bp = blockIdx.x, t = threadIdx.x, lane = t & 63, wid = t >> 6;
  const float v = outraw[bp * C3 + t];
  const float sq = wave_sum_f(v * v);
  if (lane == 0) red[wid] = sq;
  __syncthreads();
  const float nrm = fmaxf(sqrtf(red[0] + red[1] + red[2] + red[3]), 1e-7f);
  out3[(size_t)bp * C3 + t] = v / nrm;
}

// ---------------- launch ----------------
extern "C" void kernel_launch(void* const* d_in, const int* in_sizes, int n_in,
                              void* d_out, int out_size, void* d_ws, size_t ws_size,
                              hipStream_t stream){
  const float* feat0 = (const float*)d_in[0];
  const float* feat1 = (const float*)d_in[1];
  const float* feat2 = (const float*)d_in[2];
  const float* feat3 = (const float*)d_in[3];
  const int*   pid0  = (const int*)d_in[4];
  const int*   pid1  = (const int*)d_in[5];
  const int*   pid2  = (const int*)d_in[6];

  float* out  = (float*)d_out;
  float* out0 = out;                 // 128*64
  float* out1 = out + 8192;          // 128*128
  float* out2 = out + 24576;         // 128*256
  float* out3 = out + 57344;         // 128*256

  float* ws       = (float*)d_ws;
  float* ent_ws   = ws;                         // 8192
  int*   idx_ws   = (int*)(ws + 8192);          // 128
  float* dotsl_ws = ws + 8320;                  // 2*49*4096 = 401408
  float* dg_ws    = dotsl_ws + 401408;          // 128*4096  = 524288
  float* bmax_ws  = dg_ws + 524288;             // 128*16
  float* mrow_ws  = bmax_ws + 2048;             // 128
  float* srow_ws  = mrow_ws + 128;              // 128
  float* oraw_ws  = srow_ws + 128;              // 128*256

  sample_kernel<64, 16><<<128, 64, 0, stream>>>(feat0, pid0, out0);
  sample_kernel<128, 14><<<128, 64, 0, stream>>>(feat1, pid1, out1);
  sample_kernel<256, 12><<<128, 64, 0, stream>>>(feat2, pid2, out2);

  ldots_kernel<<<1664, 256, 0, stream>>>(feat3, dotsl_ws);
  lent_kernel<<<32, 256, 0, stream>>>(dotsl_ws, ent_ws);
  rank_select_kernel<<<128, 256, 0, stream>>>(ent_ws, idx_ws);
  gdots_kernel<<<2048, 256, 0, stream>>>(feat3, idx_ws, dg_ws, bmax_ws);
  gsm_kernel<<<128, 256, 0, stream>>>(dg_ws, bmax_ws, mrow_ws, srow_ws);
  pv_kernel<<<1024, 256, 0, stream>>>(feat3, dg_ws, mrow_ws, srow_ws, oraw_ws);
  norm_kernel<<<128, 256, 0, stream>>>(oraw_ws, out3);
}

// Round 5
// 149.537 us; speedup vs baseline: 1.2013x; 1.2013x over previous
//
#include <hip/hip_runtime.h>
#include <hip/hip_bf16.h>
#include <cstdint>
#include <cstddef>

// ---------------- wave helpers (wave64) ----------------
__device__ __forceinline__ float wave_max_f(float v){
  #pragma unroll
  for (int m = 32; m; m >>= 1) v = fmaxf(v, __shfl_xor(v, m));
  return v;
}
__device__ __forceinline__ float wave_sum_f(float v){
  #pragma unroll
  for (int m = 32; m; m >>= 1) v += __shfl_xor(v, m);
  return v;
}
__device__ __forceinline__ int wave_sum_i(int v){
  #pragma unroll
  for (int m = 32; m; m >>= 1) v += __shfl_xor(v, m);
  return v;
}

// ---------------- _sample_early: gather + normalize ----------------
template<int C, int LOGHW>
__global__ __launch_bounds__(64)
void sample_kernel(const float* __restrict__ feat, const int* __restrict__ pid,
                   float* __restrict__ out){
  const int r = blockIdx.x;          // 0..127
  const int b = r >> 6, p = r & 63;
  const int lane = threadIdx.x;      // 0..63
  const int l = pid[p];
  const float* fb = feat + (((size_t)b * C) << LOGHW);
  constexpr int V = C / 64;
  float v[V];
  float sq = 0.f;
  #pragma unroll
  for (int i = 0; i < V; ++i){
    const int c = lane + 64 * i;
    v[i] = fb[(((size_t)c) << LOGHW) + l];
    sq += v[i] * v[i];
  }
  sq = wave_sum_f(sq);
  const float nrm = fmaxf(sqrtf(sq), 1e-7f);
  #pragma unroll
  for (int i = 0; i < V; ++i)
    out[(size_t)r * C + lane + 64 * i] = v[i] / nrm;
}

// ---------------- qs_attn constants ----------------
#define C3   256
#define HW3  4096
#define NP   64

// ---------------- local dots (scrambled faithful mapping) ----------------
// wave per (b,h,k2); lanes = w. f = k2*256 + c2 walks channels
// c0 (partial, k in [k0,49)), c0+1..c0+4 (full 49 steps, kj compile-time),
// c0+5/+6 (tail). Scalar (SALU) channel/row bookkeeping via readfirstlane;
// wave-uniform hh guards wrap 7-step row groups (loads batchable, no
// per-step branches). Window lane offsets pre-clamped; masked by *1.0/0.0
// (exact: clamped loads read finite in-row data). Accumulation order =
// ascending f, bit-identical to the simple c2 loop.
__global__ __launch_bounds__(256)
void ldots_kernel(const float* __restrict__ feat3, float* __restrict__ dotsl){
  const int blk = blockIdx.x;
  const int kg = blk % 13;
  const int bh = blk / 13;
  const int b = bh >> 6, h = bh & 63;
  const int tid = threadIdx.x, wid = tid >> 6, lane = tid & 63;
  const int k2v = kg * 4 + wid;
  if (k2v >= 49) return;
  const int k2 = __builtin_amdgcn_readfirstlane(k2v);
  const int w = lane;
  const float* fb = feat3 + ((size_t)b << 20);
  const float* frp = fb + (h << 6) + w;       // fr[l, c2] = frp[c2 << 12]
  const int f0 = k2 << 8;
  const int c0 = f0 / 49;
  const int k0 = f0 - c0 * 49;

  int   vof[7];
  float msk[7];
  #pragma unroll
  for (int kj = 0; kj < 7; ++kj){
    const int s = w + kj - 3;
    msk[kj] = ((unsigned)s < 64u) ? 1.f : 0.f;
    vof[kj] = s < 0 ? 0 : (s > 63 ? 63 : s);
  }

  float acc = 0.f;
  int c2 = 0;

  // generic (dynamic-k) step used for head/tail partial channels
  auto partial = [&](int c, int klo, int khi){
    for (int k = klo; k < khi; ++k){
      const int ki = k / 7, kj = k - (k / 7) * 7;
      const int hh = h + ki - 3;
      float wv = 0.f;
      if ((unsigned)hh < 64u){
        const int sw = w + kj - 3;
        const int swc = sw < 0 ? 0 : (sw > 63 ? 63 : sw);
        const float x = fb[((size_t)c << 12) + (hh << 6) + swc];
        wv = ((unsigned)sw < 64u) ? x : 0.f;
      }
      acc = fmaf(wv, frp[(size_t)c2 << 12], acc);
      ++c2;
    }
  };

  // ---- head: channel c0, k in [k0, 49)
  partial(c0, k0, 49);

  // ---- body: 4 full channels, branch-free 7-step row groups
  #pragma unroll
  for (int j = 1; j <= 4; ++j){
    const int c = c0 + j;
    const float* chan = fb + ((size_t)c << 12);
    #pragma unroll
    for (int ki = 0; ki < 7; ++ki){
      const int hh = h + ki - 3;
      if ((unsigned)hh < 64u){                 // wave-uniform scalar branch
        const float* row = chan + (hh << 6);
        #pragma unroll
        for (int kj = 0; kj < 7; ++kj){
          const float x = row[vof[kj]];
          acc = fmaf(x * msk[kj], frp[(size_t)(c2 + ki * 7 + kj) << 12], acc);
        }
      }
      // hh out of range -> all terms exactly 0; skipping is bit-exact
    }
    c2 += 49;
  }

  // ---- tail: channel c0+5 (and c0+6 when k0 > 38)
  {
    const int rem = 11 + k0;                   // 256 - (49-k0) - 196
    const int khi = rem < 49 ? rem : 49;
    partial(c0 + 5, 0, khi);
    if (rem > 49) partial(c0 + 6, 0, rem - 49);
  }

  dotsl[(((size_t)(b * 49 + k2)) << 12) + (h << 6) + w] = acc;
}

// ---------------- local entropy (softmax over 49, k-major layout) ----------
__global__ __launch_bounds__(256)
void lent_kernel(const float* __restrict__ dotsl, float* __restrict__ ent){
  const int blk = blockIdx.x;       // 32
  const int b = blk >> 4;
  const int l = ((blk & 15) << 8) + threadIdx.x;
  const float* dl = dotsl + (((size_t)b * 49) << 12);
  float m = -INFINITY;
  #pragma unroll
  for (int k = 0; k < 49; ++k) m = fmaxf(m, dl[((size_t)k << 12) + l]);
  float s = 0.f, ts = 0.f;
  #pragma unroll
  for (int k = 0; k < 49; ++k){
    const float d = dl[((size_t)k << 12) + l] - m;
    const float e = expf(d);
    s += e; ts += e * d;
  }
  ent[b * HW3 + l] = logf(s) - ts / s;
}

// ---------------- rank-based top-64 selection (stable, exact) -------------
__global__ __launch_bounds__(256)
void rank_select_kernel(const float* __restrict__ ent, int* __restrict__ idx){
  __shared__ unsigned long long keys[HW3];   // 32 KB
  const int blk = blockIdx.x;
  const int b  = blk >> 6;
  const int cg = blk & 63;                   // 64 candidates per block
  const int t = threadIdx.x, wid = t >> 6, lane = t & 63;
  for (int i = t; i < HW3; i += 256){
    const float e = ent[b * HW3 + i];
    unsigned u = __float_as_uint(e);
    u = (u & 0x80000000u) ? ~u : (u | 0x80000000u);
    keys[i] = ((unsigned long long)u << 32) | (unsigned)i;
  }
  __syncthreads();
  #pragma unroll
  for (int j = 0; j < 16; ++j){
    const int cand = (cg << 6) + (wid << 4) + j;
    const unsigned long long kc = keys[cand];
    int cnt = 0;
    #pragma unroll 8
    for (int i = lane; i < HW3; i += 64)
      cnt += (keys[i] < kc) ? 1 : 0;
    cnt = wave_sum_i(cnt);
    if (lane == 0 && cnt < NP) idx[b * NP + cnt] = cand;
  }
}

// ---------------- global dots: grid (b,p) x 16 l-chunks -------------------
__global__ __launch_bounds__(256)
void gdots_kernel(const float* __restrict__ feat3, const int* __restrict__ idx,
                  float* __restrict__ dg, float* __restrict__ bmax){
  __shared__ float q_sh[C3];
  __shared__ float red[4];
  const int blk = blockIdx.x;       // 2048
  const int bp = blk >> 4, lc = blk & 15;
  const int b = bp >> 6;
  const int t = threadIdx.x, lane = t & 63, wid = t >> 6;
  const float* fb = feat3 + ((size_t)b << 20);
  const int pidx = idx[bp];
  q_sh[t] = fb[((size_t)t << 12) + pidx];
  __syncthreads();
  const int l = (lc << 8) + t;
  float acc = 0.f;
  #pragma unroll 8
  for (int c = 0; c < C3; ++c) acc += fb[((size_t)c << 12) + l] * q_sh[c];
  dg[((size_t)bp << 12) + l] = acc;
  const float m = wave_max_f(acc);
  if (lane == 0) red[wid] = m;
  __syncthreads();
  if (t == 0) bmax[bp * 16 + lc] = fmaxf(fmaxf(red[0], red[1]), fmaxf(red[2], red[3]));
}

// ---------------- global softmax stats ----------------
__global__ __launch_bounds__(256)
void gsm_kernel(const float* __restrict__ dg, const float* __restrict__ bmax,
                float* __restrict__ mrow, float* __restrict__ srow){
  __shared__ float red[4];
  const int bp = blockIdx.x, t = threadIdx.x, lane = t & 63, wid = t >> 6;
  float m = -INFINITY;
  #pragma unroll
  for (int i = 0; i < 16; ++i) m = fmaxf(m, bmax[bp * 16 + i]);
  float s = 0.f;
  #pragma unroll
  for (int i = 0; i < 16; ++i) s += expf(dg[((size_t)bp << 12) + (i << 8) + t] - m);
  s = wave_sum_f(s);
  if (lane == 0) red[wid] = s;
  __syncthreads();
  if (t == 0){
    mrow[bp] = m;
    srow[bp] = 1.f / (red[0] + red[1] + red[2] + red[3]);
  }
}

// ---------------- PV: grid (b,p) x 8 channel-groups -----------------------
__global__ __launch_bounds__(256)
void pv_kernel(const float* __restrict__ feat3, const float* __restrict__ dg,
               const float* __restrict__ mrow, const float* __restrict__ srow,
               float* __restrict__ outraw){
  __shared__ float p_sh[HW3];
  const int blk = blockIdx.x;       // 1024
  const int bp = blk >> 3, cg = blk & 7;
  const int b = bp >> 6;
  const int t = threadIdx.x, lane = t & 63, wid = t >> 6;
  const float* fb = feat3 + ((size_t)b << 20);
  const float m = mrow[bp], inv = srow[bp];
  #pragma unroll
  for (int i = 0; i < 16; ++i){
    const int l = (i << 8) + t;
    p_sh[l] = expf(dg[((size_t)bp << 12) + l] - m) * inv;
  }
  __syncthreads();
  const float4* pv4 = reinterpret_cast<const float4*>(p_sh);
  #pragma unroll
  for (int j = 0; j < 8; ++j){
    const int c = (cg << 5) + (wid << 3) + j;
    const float4* rv = reinterpret_cast<const float4*>(fb + ((size_t)c << 12));
    float s = 0.f;
    #pragma unroll
    for (int i = 0; i < 16; ++i){
      const float4 a = rv[(i << 6) + lane];
      const float4 pp = pv4[(i << 6) + lane];
      s += a.x * pp.x + a.y * pp.y + a.z * pp.z + a.w * pp.w;
    }
    s = wave_sum_f(s);
    if (lane == 0) outraw[bp * C3 + c] = s;
  }
}

// ---------------- normalize rows of 256 ----------------
__global__ __launch_bounds__(256)
void norm_kernel(const float* __restrict__ outraw, float* __restrict__ out3){
  __shared__ float red[4];
  const int bp = blockIdx.x, t = threadIdx.x, lane = t & 63, wid = t >> 6;
  const float v = outraw[bp * C3 + t];
  const float sq = wave_sum_f(v * v);
  if (lane == 0) red[wid] = sq;
  __syncthreads();
  const float nrm = fmaxf(sqrtf(red[0] + red[1] + red[2] + red[3]), 1e-7f);
  out3[(size_t)bp * C3 + t] = v / nrm;
}

// ---------------- launch ----------------
extern "C" void kernel_launch(void* const* d_in, const int* in_sizes, int n_in,
                              void* d_out, int out_size, void* d_ws, size_t ws_size,
                              hipStream_t stream){
  const float* feat0 = (const float*)d_in[0];
  const float* feat1 = (const float*)d_in[1];
  const float* feat2 = (const float*)d_in[2];
  const float* feat3 = (const float*)d_in[3];
  const int*   pid0  = (const int*)d_in[4];
  const int*   pid1  = (const int*)d_in[5];
  const int*   pid2  = (const int*)d_in[6];

  float* out  = (float*)d_out;
  float* out0 = out;                 // 128*64
  float* out1 = out + 8192;          // 128*128
  float* out2 = out + 24576;         // 128*256
  float* out3 = out + 57344;         // 128*256

  float* ws       = (float*)d_ws;
  float* ent_ws   = ws;                         // 8192
  int*   idx_ws   = (int*)(ws + 8192);          // 128
  float* dotsl_ws = ws + 8320;                  // 2*49*4096 = 401408
  float* dg_ws    = dotsl_ws + 401408;          // 128*4096  = 524288
  float* bmax_ws  = dg_ws + 524288;             // 128*16
  float* mrow_ws  = bmax_ws + 2048;             // 128
  float* srow_ws  = mrow_ws + 128;              // 128
  float* oraw_ws  = srow_ws + 128;              // 128*256

  sample_kernel<64, 16><<<128, 64, 0, stream>>>(feat0, pid0, out0);
  sample_kernel<128, 14><<<128, 64, 0, stream>>>(feat1, pid1, out1);
  sample_kernel<256, 12><<<128, 64, 0, stream>>>(feat2, pid2, out2);

  ldots_kernel<<<1664, 256, 0, stream>>>(feat3, dotsl_ws);
  lent_kernel<<<32, 256, 0, stream>>>(dotsl_ws, ent_ws);
  rank_select_kernel<<<128, 256, 0, stream>>>(ent_ws, idx_ws);
  gdots_kernel<<<2048, 256, 0, stream>>>(feat3, idx_ws, dg_ws, bmax_ws);
  gsm_kernel<<<128, 256, 0, stream>>>(dg_ws, bmax_ws, mrow_ws, srow_ws);
  pv_kernel<<<1024, 256, 0, stream>>>(feat3, dg_ws, mrow_ws, srow_ws, oraw_ws);
  norm_kernel<<<128, 256, 0, stream>>>(oraw_ws, out3);
}

// Round 6
// 124.359 us; speedup vs baseline: 1.4445x; 1.2025x over previous
//
#include <hip/hip_runtime.h>
#include <hip/hip_bf16.h>
#include <cstdint>
#include <cstddef>

// ---------------- wave helpers (wave64) ----------------
__device__ __forceinline__ float wave_max_f(float v){
  #pragma unroll
  for (int m = 32; m; m >>= 1) v = fmaxf(v, __shfl_xor(v, m));
  return v;
}
__device__ __forceinline__ float wave_sum_f(float v){
  #pragma unroll
  for (int m = 32; m; m >>= 1) v += __shfl_xor(v, m);
  return v;
}
__device__ __forceinline__ int wave_sum_i(int v){
  #pragma unroll
  for (int m = 32; m; m >>= 1) v += __shfl_xor(v, m);
  return v;
}

// ---------------- _sample_early: gather + normalize ----------------
template<int C, int LOGHW>
__global__ __launch_bounds__(64)
void sample_kernel(const float* __restrict__ feat, const int* __restrict__ pid,
                   float* __restrict__ out){
  const int r = blockIdx.x;          // 0..127
  const int b = r >> 6, p = r & 63;
  const int lane = threadIdx.x;      // 0..63
  const int l = pid[p];
  const float* fb = feat + (((size_t)b * C) << LOGHW);
  constexpr int V = C / 64;
  float v[V];
  float sq = 0.f;
  #pragma unroll
  for (int i = 0; i < V; ++i){
    const int c = lane + 64 * i;
    v[i] = fb[(((size_t)c) << LOGHW) + l];
    sq += v[i] * v[i];
  }
  sq = wave_sum_f(sq);
  const float nrm = fmaxf(sqrtf(sq), 1e-7f);
  #pragma unroll
  for (int i = 0; i < V; ++i)
    out[(size_t)r * C + lane + 64 * i] = v[i] / nrm;
}

// ---------------- qs_attn constants ----------------
#define C3   256
#define HW3  4096
#define NP   64

// ---------------- local dots (scrambled faithful mapping) ----------------
// XCD-swizzled: 1664 blocks = 8 XCDs x 208; contiguous work (= contiguous
// (b,h) rows, kg inner) per XCD -> ~1.4 MB L2 working set per XCD.
__global__ __launch_bounds__(256)
void ldots_kernel(const float* __restrict__ feat3, float* __restrict__ dotsl){
  const int raw = blockIdx.x;
  const int blk = (raw & 7) * 208 + (raw >> 3);   // bijective: 1664 = 8*208
  const int kg = blk % 13;
  const int bh = blk / 13;
  const int b = bh >> 6, h = bh & 63;
  const int tid = threadIdx.x, wid = tid >> 6, lane = tid & 63;
  const int k2v = kg * 4 + wid;
  if (k2v >= 49) return;
  const int k2 = __builtin_amdgcn_readfirstlane(k2v);
  const int w = lane;
  const float* fb = feat3 + ((size_t)b << 20);
  const float* frp = fb + (h << 6) + w;       // fr[l, c2] = frp[c2 << 12]
  const int f0 = k2 << 8;
  const int c0 = f0 / 49;
  const int k0 = f0 - c0 * 49;

  int   vof[7];
  float msk[7];
  #pragma unroll
  for (int kj = 0; kj < 7; ++kj){
    const int s = w + kj - 3;
    msk[kj] = ((unsigned)s < 64u) ? 1.f : 0.f;
    vof[kj] = s < 0 ? 0 : (s > 63 ? 63 : s);
  }

  float acc = 0.f;
  int c2 = 0;

  auto partial = [&](int c, int klo, int khi){
    for (int k = klo; k < khi; ++k){
      const int ki = k / 7, kj = k - (k / 7) * 7;
      const int hh = h + ki - 3;
      float wv = 0.f;
      if ((unsigned)hh < 64u){
        const int sw = w + kj - 3;
        const int swc = sw < 0 ? 0 : (sw > 63 ? 63 : sw);
        const float x = fb[((size_t)c << 12) + (hh << 6) + swc];
        wv = ((unsigned)sw < 64u) ? x : 0.f;
      }
      acc = fmaf(wv, frp[(size_t)c2 << 12], acc);
      ++c2;
    }
  };

  partial(c0, k0, 49);

  #pragma unroll
  for (int j = 1; j <= 4; ++j){
    const int c = c0 + j;
    const float* chan = fb + ((size_t)c << 12);
    #pragma unroll
    for (int ki = 0; ki < 7; ++ki){
      const int hh = h + ki - 3;
      if ((unsigned)hh < 64u){                 // wave-uniform scalar branch
        const float* row = chan + (hh << 6);
        #pragma unroll
        for (int kj = 0; kj < 7; ++kj){
          const float x = row[vof[kj]];
          acc = fmaf(x * msk[kj], frp[(size_t)(c2 + ki * 7 + kj) << 12], acc);
        }
      }
    }
    c2 += 49;
  }

  {
    const int rem = 11 + k0;
    const int khi = rem < 49 ? rem : 49;
    partial(c0 + 5, 0, khi);
    if (rem > 49) partial(c0 + 6, 0, rem - 49);
  }

  dotsl[(((size_t)(b * 49 + k2)) << 12) + (h << 6) + w] = acc;
}

// ---------------- local entropy (softmax over 49, k-major layout) ----------
__global__ __launch_bounds__(256)
void lent_kernel(const float* __restrict__ dotsl, float* __restrict__ ent){
  const int blk = blockIdx.x;       // 32
  const int b = blk >> 4;
  const int l = ((blk & 15) << 8) + threadIdx.x;
  const float* dl = dotsl + (((size_t)b * 49) << 12);
  float m = -INFINITY;
  #pragma unroll
  for (int k = 0; k < 49; ++k) m = fmaxf(m, dl[((size_t)k << 12) + l]);
  float s = 0.f, ts = 0.f;
  #pragma unroll
  for (int k = 0; k < 49; ++k){
    const float d = dl[((size_t)k << 12) + l] - m;
    const float e = expf(d);
    s += e; ts += e * d;
  }
  ent[b * HW3 + l] = logf(s) - ts / s;
}

// ---------------- rank-based top-64 selection (stable, exact) -------------
__global__ __launch_bounds__(256)
void rank_select_kernel(const float* __restrict__ ent, int* __restrict__ idx){
  __shared__ unsigned long long keys[HW3];   // 32 KB
  const int blk = blockIdx.x;
  const int b  = blk >> 6;
  const int cg = blk & 63;                   // 64 candidates per block
  const int t = threadIdx.x, wid = t >> 6, lane = t & 63;
  for (int i = t; i < HW3; i += 256){
    const float e = ent[b * HW3 + i];
    unsigned u = __float_as_uint(e);
    u = (u & 0x80000000u) ? ~u : (u | 0x80000000u);
    keys[i] = ((unsigned long long)u << 32) | (unsigned)i;
  }
  __syncthreads();
  #pragma unroll
  for (int j = 0; j < 16; ++j){
    const int cand = (cg << 6) + (wid << 4) + j;
    const unsigned long long kc = keys[cand];
    int cnt = 0;
    #pragma unroll 8
    for (int i = lane; i < HW3; i += 64)
      cnt += (keys[i] < kc) ? 1 : 0;
    cnt = wave_sum_i(cnt);
    if (lane == 0 && cnt < NP) idx[b * NP + cnt] = cand;
  }
}

// ---------------- global dots: 4 query rows per block ---------------------
// grid 512 = 8 XCD x 64 ; work = ((b*16+pg)<<4)|lc ; block computes dots of
// 4 q-rows vs one 256-l chunk (stream shared across the 4 rows).
__global__ __launch_bounds__(256)
void gdots_kernel(const float* __restrict__ feat3, const int* __restrict__ idx,
                  float* __restrict__ dg, float* __restrict__ bmax){
  __shared__ float4 q_int[C3];     // q_int[c] = {q0,q1,q2,q3}[c]
  __shared__ float red4[4][4];     // [wid][q]
  const int raw = blockIdx.x;
  const int work = (raw & 7) * 64 + (raw >> 3);   // 512 = 8*64
  const int bpg = work >> 4, lc = work & 15;      // bpg in 0..31
  const int b = bpg >> 4;
  const int bp0 = (b << 6) + ((bpg & 15) << 2);
  const int t = threadIdx.x, lane = t & 63, wid = t >> 6;
  const float* fb = feat3 + ((size_t)b << 20);
  {
    float4 qv;
    qv.x = fb[((size_t)t << 12) + idx[bp0 + 0]];
    qv.y = fb[((size_t)t << 12) + idx[bp0 + 1]];
    qv.z = fb[((size_t)t << 12) + idx[bp0 + 2]];
    qv.w = fb[((size_t)t << 12) + idx[bp0 + 3]];
    q_int[t] = qv;
  }
  __syncthreads();
  const int l = (lc << 8) + t;
  float a0 = 0.f, a1 = 0.f, a2 = 0.f, a3 = 0.f;
  #pragma unroll 8
  for (int c = 0; c < C3; ++c){
    const float fv = fb[((size_t)c << 12) + l];
    const float4 q = q_int[c];
    a0 = fmaf(fv, q.x, a0); a1 = fmaf(fv, q.y, a1);
    a2 = fmaf(fv, q.z, a2); a3 = fmaf(fv, q.w, a3);
  }
  dg[((size_t)(bp0 + 0) << 12) + l] = a0;
  dg[((size_t)(bp0 + 1) << 12) + l] = a1;
  dg[((size_t)(bp0 + 2) << 12) + l] = a2;
  dg[((size_t)(bp0 + 3) << 12) + l] = a3;
  const float m0 = wave_max_f(a0), m1 = wave_max_f(a1);
  const float m2 = wave_max_f(a2), m3 = wave_max_f(a3);
  if (lane == 0){
    red4[wid][0] = m0; red4[wid][1] = m1;
    red4[wid][2] = m2; red4[wid][3] = m3;
  }
  __syncthreads();
  if (t < 4){
    const float m = fmaxf(fmaxf(red4[0][t], red4[1][t]),
                          fmaxf(red4[2][t], red4[3][t]));
    bmax[(bp0 + t) * 16 + lc] = m;
  }
}

// ---------------- global softmax stats ----------------
__global__ __launch_bounds__(256)
void gsm_kernel(const float* __restrict__ dg, const float* __restrict__ bmax,
                float* __restrict__ mrow, float* __restrict__ srow){
  __shared__ float red[4];
  const int bp = blockIdx.x, t = threadIdx.x, lane = t & 63, wid = t >> 6;
  float m = -INFINITY;
  #pragma unroll
  for (int i = 0; i < 16; ++i) m = fmaxf(m, bmax[bp * 16 + i]);
  float s = 0.f;
  #pragma unroll
  for (int i = 0; i < 16; ++i) s += expf(dg[((size_t)bp << 12) + (i << 8) + t] - m);
  s = wave_sum_f(s);
  if (lane == 0) red[wid] = s;
  __syncthreads();
  if (t == 0){
    mrow[bp] = m;
    srow[bp] = 1.f / (red[0] + red[1] + red[2] + red[3]);
  }
}

// ---------------- PV: 4 query rows x 32 channels per block ----------------
// grid 256 = 8 XCD x 32 ; work = ((b*16+pg)<<3)|cg. Probs for the 4 rows
// packed float4-per-l in LDS (XOR swizzle vs bank conflicts); each streamed
// float4 of F feeds 16 FMAs.
#define PSW(l) ((l) ^ (((l) >> 3) & 7))
__global__ __launch_bounds__(256)
void pv_kernel(const float* __restrict__ feat3, const float* __restrict__ dg,
               const float* __restrict__ mrow, const float* __restrict__ srow,
               float* __restrict__ outraw){
  __shared__ float4 p_int[HW3];    // 64 KB
  const int raw = blockIdx.x;
  const int work = (raw & 7) * 32 + (raw >> 3);   // 256 = 8*32
  const int bpg = work >> 3, cg = work & 7;
  const int b = bpg >> 4;
  const int bp0 = (b << 6) + ((bpg & 15) << 2);
  const int t = threadIdx.x, lane = t & 63, wid = t >> 6;
  const float* fb = feat3 + ((size_t)b << 20);
  const float m0 = mrow[bp0 + 0], i0 = srow[bp0 + 0];
  const float m1 = mrow[bp0 + 1], i1 = srow[bp0 + 1];
  const float m2 = mrow[bp0 + 2], i2 = srow[bp0 + 2];
  const float m3 = mrow[bp0 + 3], i3 = srow[bp0 + 3];
  #pragma unroll
  for (int i = 0; i < 16; ++i){
    const int l = (i << 8) + t;
    float4 pv;
    pv.x = expf(dg[((size_t)(bp0 + 0) << 12) + l] - m0) * i0;
    pv.y = expf(dg[((size_t)(bp0 + 1) << 12) + l] - m1) * i1;
    pv.z = expf(dg[((size_t)(bp0 + 2) << 12) + l] - m2) * i2;
    pv.w = expf(dg[((size_t)(bp0 + 3) << 12) + l] - m3) * i3;
    p_int[PSW(l)] = pv;
  }
  __syncthreads();
  float s[8][4];
  #pragma unroll
  for (int j = 0; j < 8; ++j)
    #pragma unroll
    for (int q = 0; q < 4; ++q) s[j][q] = 0.f;

  const int cbase = (cg << 5) + (wid << 3);
  for (int i = 0; i < 16; ++i){
    const int l4 = (i << 6) + lane;          // float4-chunk index over l
    const float4 p0 = p_int[PSW(4 * l4 + 0)];
    const float4 p1 = p_int[PSW(4 * l4 + 1)];
    const float4 p2 = p_int[PSW(4 * l4 + 2)];
    const float4 p3 = p_int[PSW(4 * l4 + 3)];
    #pragma unroll
    for (int j = 0; j < 8; ++j){
      const float4 a = *reinterpret_cast<const float4*>(
          fb + (((size_t)(cbase + j)) << 12) + 4 * (size_t)l4);
      s[j][0] += a.x * p0.x + a.y * p1.x + a.z * p2.x + a.w * p3.x;
      s[j][1] += a.x * p0.y + a.y * p1.y + a.z * p2.y + a.w * p3.y;
      s[j][2] += a.x * p0.z + a.y * p1.z + a.z * p2.z + a.w * p3.z;
      s[j][3] += a.x * p0.w + a.y * p1.w + a.z * p2.w + a.w * p3.w;
    }
  }
  #pragma unroll
  for (int j = 0; j < 8; ++j){
    #pragma unroll
    for (int q = 0; q < 4; ++q){
      const float v = wave_sum_f(s[j][q]);
      if (lane == 0) outraw[(bp0 + q) * C3 + cbase + j] = v;
    }
  }
}

// ---------------- normalize rows of 256 ----------------
__global__ __launch_bounds__(256)
void norm_kernel(const float* __restrict__ outraw, float* __restrict__ out3){
  __shared__ float red[4];
  const int bp = blockIdx.x, t = threadIdx.x, lane = t & 63, wid = t >> 6;
  const float v = outraw[bp * C3 + t];
  const float sq = wave_sum_f(v * v);
  if (lane == 0) red[wid] = sq;
  __syncthreads();
  const float nrm = fmaxf(sqrtf(red[0] + red[1] + red[2] + red[3]), 1e-7f);
  out3[(size_t)bp * C3 + t] = v / nrm;
}

// ---------------- launch ----------------
extern "C" void kernel_launch(void* const* d_in, const int* in_sizes, int n_in,
                              void* d_out, int out_size, void* d_ws, size_t ws_size,
                              hipStream_t stream){
  const float* feat0 = (const float*)d_in[0];
  const float* feat1 = (const float*)d_in[1];
  const float* feat2 = (const float*)d_in[2];
  const float* feat3 = (const float*)d_in[3];
  const int*   pid0  = (const int*)d_in[4];
  const int*   pid1  = (const int*)d_in[5];
  const int*   pid2  = (const int*)d_in[6];

  float* out  = (float*)d_out;
  float* out0 = out;                 // 128*64
  float* out1 = out + 8192;          // 128*128
  float* out2 = out + 24576;         // 128*256
  float* out3 = out + 57344;         // 128*256

  float* ws       = (float*)d_ws;
  float* ent_ws   = ws;                         // 8192
  int*   idx_ws   = (int*)(ws + 8192);          // 128
  float* dotsl_ws = ws + 8320;                  // 2*49*4096 = 401408
  float* dg_ws    = dotsl_ws + 401408;          // 128*4096  = 524288
  float* bmax_ws  = dg_ws + 524288;             // 128*16
  float* mrow_ws  = bmax_ws + 2048;             // 128
  float* srow_ws  = mrow_ws + 128;              // 128
  float* oraw_ws  = srow_ws + 128;              // 128*256

  sample_kernel<64, 16><<<128, 64, 0, stream>>>(feat0, pid0, out0);
  sample_kernel<128, 14><<<128, 64, 0, stream>>>(feat1, pid1, out1);
  sample_kernel<256, 12><<<128, 64, 0, stream>>>(feat2, pid2, out2);

  ldots_kernel<<<1664, 256, 0, stream>>>(feat3, dotsl_ws);
  lent_kernel<<<32, 256, 0, stream>>>(dotsl_ws, ent_ws);
  rank_select_kernel<<<128, 256, 0, stream>>>(ent_ws, idx_ws);
  gdots_kernel<<<512, 256, 0, stream>>>(feat3, idx_ws, dg_ws, bmax_ws);
  gsm_kernel<<<128, 256, 0, stream>>>(dg_ws, bmax_ws, mrow_ws, srow_ws);
  pv_kernel<<<256, 256, 0, stream>>>(feat3, dg_ws, mrow_ws, srow_ws, oraw_ws);
  norm_kernel<<<128, 256, 0, stream>>>(oraw_ws, out3);
}